// Round 13
// baseline (1425.976 us; speedup 1.0000x reference)
//
#include <hip/hip_runtime.h>
#include <math.h>

#define NCLS 64
#define KS 5
#define DD 256
#define NQ 8192   // NCLS*128
#define KNB 10
#define QK 16     // per-quarter candidate list depth
#define CAND 64   // 4 quarters * QK

typedef __attribute__((ext_vector_type(8))) short short8;   // 8 bf16 bit-patterns (4 VGPRs)
typedef __attribute__((ext_vector_type(4))) float f32x4;    // MFMA C/D frag

// row index in x (fp32 row units) of query g
__device__ __forceinline__ int qrow(int g) { return (g >> 7) * 133 + KS + (g & 127); }

__device__ __forceinline__ unsigned short bf16_rne(float f) {
    unsigned int u = __float_as_uint(f);
    u += 0x7fffu + ((u >> 16) & 1u);
    return (unsigned short)(u >> 16);
}
__device__ __forceinline__ float bf16_to_f(unsigned short h) {
    return __uint_as_float(((unsigned int)h) << 16);
}

__device__ __forceinline__ float blk_reduce_sum(float v, float* red) {
    int t = threadIdx.x;
    red[t] = v; __syncthreads();
    for (int off = 128; off > 0; off >>= 1) {
        if (t < off) red[t] += red[t + off];
        __syncthreads();
    }
    float r = red[0];
    __syncthreads();
    return r;
}

__device__ __forceinline__ float blk_reduce_max(float v, float* red) {
    int t = threadIdx.x;
    red[t] = v; __syncthreads();
    for (int off = 128; off > 0; off >>= 1) {
        if (t < off) red[t] = fmaxf(red[t], red[t + off]);
        __syncthreads();
    }
    float r = red[0];
    __syncthreads();
    return r;
}

// ---------- K0: bf16 hi/lo split of query rows + qInv ----------
__global__ __launch_bounds__(256) void split_kernel(const float* __restrict__ x,
                                                    unsigned short* __restrict__ xh,
                                                    unsigned short* __restrict__ xl,
                                                    float* __restrict__ qInv) {
    __shared__ float red[256];
    int g = blockIdx.x, t = threadIdx.x;
    float v = x[(long)qrow(g) * DD + t];
    unsigned short h = bf16_rne(v);
    float hf = bf16_to_f(h);
    unsigned short l = bf16_rne(v - hf);
    xh[g * DD + t] = h;
    xl[g * DD + t] = l;
    float n2 = blk_reduce_sum(v * v, red);
    if (t == 0) qInv[g] = 1.f / sqrtf(n2);
}

// ---------- K1: proto, pn, self_sim ----------
__global__ __launch_bounds__(256) void proto_kernel(const float* __restrict__ x,
                                                    float* proto, float* pn, float* selfs) {
    __shared__ float red[256];
    int c = blockIdx.x, t = threadIdx.x;
    float s = 0.f;
    for (int j = 0; j < KS; j++) s += x[(long)(c * 133 + j) * DD + t];
    float p = s / 5.0f;
    proto[c * DD + t] = p;
    float n2 = blk_reduce_sum(p * p, red);
    float pv = p / sqrtf(n2);
    pn[c * DD + t] = pv;
    float ss = blk_reduce_sum(pv * pv, red);
    if (t == 0) selfs[c] = ss;
}

// ---------- K2: pre_sim argmax per query ----------
__global__ __launch_bounds__(256) void presim_kernel(const float* __restrict__ x,
                                                     const float* __restrict__ qInv,
                                                     const float* __restrict__ pn,
                                                     float* pre_max, int* pre_label) {
    __shared__ float qs[256];
    __shared__ float part[256];
    __shared__ float sims[64];
    int g = blockIdx.x, t = threadIdx.x;
    qs[t] = x[(long)qrow(g) * DD + t];
    __syncthreads();
    int c = t >> 2, tl = t & 3;
    float s = 0.f;
    for (int u = 0; u < 64; u++) s += qs[tl * 64 + u] * pn[c * DD + tl * 64 + u];
    part[t] = s; __syncthreads();
    if (tl == 0) sims[c] = part[t] + part[t + 1] + part[t + 2] + part[t + 3];
    __syncthreads();
    if (t == 0) {
        float best = sims[0]; int bi = 0;
        for (int c2 = 1; c2 < 64; c2++)
            if (sims[c2] > best) { best = sims[c2]; bi = c2; }
        pre_max[g] = best * qInv[g];
        pre_label[g] = bi;
    }
}

// ---------- K3: adapted prototypes (normalized) ----------
__global__ __launch_bounds__(256) void adapt_proto_kernel(const float* __restrict__ x,
                                                          const float* __restrict__ proto,
                                                          const float* __restrict__ selfs,
                                                          const float* __restrict__ pre_max,
                                                          const int* __restrict__ pre_label,
                                                          float* apn) {
    __shared__ float red[256];
    int c = blockIdx.x, t = threadIdx.x;
    float lm = -INFINITY;
    for (int g = t; g < NQ; g += 256)
        if (pre_label[g] == c) lm = fmaxf(lm, pre_max[g]);
    float m = fmaxf(blk_reduce_max(lm, red), selfs[c]);
    float ls = 0.f;
    for (int g = t; g < NQ; g += 256)
        if (pre_label[g] == c) ls += expf(pre_max[g] - m);
    float es = expf(selfs[c] - m);
    float Z = blk_reduce_sum(ls, red) + es;
    float acc = es * proto[c * DD + t];
    for (int g = 0; g < NQ; g++) {
        if (pre_label[g] == c)
            acc += expf(pre_max[g] - m) * x[(long)qrow(g) * DD + t];
    }
    float ap = acc / Z;
    float n2 = blk_reduce_sum(ap * ap, red);
    apn[c * DD + t] = ap / sqrtf(n2);
}

// ---------- K4: bf16 MFMA (hi/lo) coarse scores -> per-quarter top-16 CANDIDATE indices ----------
__global__ __launch_bounds__(256) void simtopk_kernel(const unsigned short* __restrict__ xh,
                                                      const unsigned short* __restrict__ xl,
                                                      const float* __restrict__ qInv,
                                                      int* __restrict__ topi4) {
    __shared__ __align__(16) unsigned short Bs[2][16][264];  // [plane][col][k] 16.9 KB
    __shared__ float Sw[4][16 * 17];                         // per-wave scores
    __shared__ float lv[4][16][QK];
    __shared__ int   li[4][16][QK];

    const int t = threadIdx.x;
    const int b = blockIdx.x;
    const int rb = b >> 2;
    const int qt = b & 3;
    const int row0 = rb * 64;
    const int col0 = qt * 2048;

    const int wv = t >> 6;
    const int lane = t & 63;
    const int qd = lane >> 4;
    const int nn = lane & 15;

    const int sp   = t >> 7;
    const int scol = (t >> 3) & 15;
    const int sseg = t & 7;

    for (int s = t; s < 4 * 16 * QK; s += 256) {
        (&lv[0][0][0])[s] = -INFINITY;
        (&li[0][0][0])[s] = 0x7fffffff;
    }

    const int arow = (row0 + wv * 16 + nn) * DD;
    short8 ah[8], al[8];
    #pragma unroll
    for (int kc = 0; kc < 8; kc++) {
        ah[kc] = *(const short8*)(xh + arow + kc * 32 + qd * 8);
        al[kc] = *(const short8*)(xl + arow + kc * 32 + qd * 8);
    }

    const float ainv = qInv[row0 + wv * 16 + nn];
    float* S = &Sw[wv][0];
    float thr = -INFINITY;

    const unsigned short* splane = sp ? xl : xh;

    __syncthreads();

    for (int ct = 0; ct < 128; ct++) {
        const int jb = col0 + ct * 16;
        {
            const unsigned short* src = splane + (jb + scol) * DD + sseg * 8;
            unsigned short* dst = &Bs[sp][scol][sseg * 8];
            #pragma unroll
            for (int pass = 0; pass < 4; pass++)
                *(uint4*)(dst + pass * 64) = *(const uint4*)(src + pass * 64);
        }
        __syncthreads();
        f32x4 acc = {0.f, 0.f, 0.f, 0.f};
        #pragma unroll
        for (int kc = 0; kc < 8; kc++) {
            short8 bh = *(const short8*)&Bs[0][nn][kc * 32 + qd * 8];
            short8 bl = *(const short8*)&Bs[1][nn][kc * 32 + qd * 8];
            acc = __builtin_amdgcn_mfma_f32_16x16x32_bf16(ah[kc], bh, acc, 0, 0, 0);
            acc = __builtin_amdgcn_mfma_f32_16x16x32_bf16(ah[kc], bl, acc, 0, 0, 0);
            acc = __builtin_amdgcn_mfma_f32_16x16x32_bf16(al[kc], bh, acc, 0, 0, 0);
        }
        #pragma unroll
        for (int r = 0; r < 4; r++)
            S[(4 * qd + r) * 17 + nn] = acc[r];
        __syncthreads();
        if (lane < 16) {
            float* Lv = &lv[wv][lane][0];
            int*   Li = &li[wv][lane][0];
            #pragma unroll 1
            for (int j = 0; j < 16; j++) {
                float v = S[lane * 17 + j] * ainv * qInv[jb + j];
                if (v > thr) {
                    int p = QK - 1;
                    while (p > 0 && Lv[p - 1] < v) {
                        Lv[p] = Lv[p - 1]; Li[p] = Li[p - 1]; p--;
                    }
                    Lv[p] = v; Li[p] = jb + j;
                    thr = Lv[QK - 1];
                }
            }
        }
        __syncthreads();
    }

    if (t < 64) {
        const int w = t >> 4, r = t & 15;
        const int g = row0 + w * 16 + r;
        for (int s = 0; s < QK; s++)
            topi4[(g * 4 + qt) * QK + s] = li[w][r][s];
    }
}

// ---------- K5: exact fp32 rescoring (strict-k fmaf, reproduces R11 scores) + top-10 ----------
__global__ __launch_bounds__(256) void rescore_kernel(const float* __restrict__ x,
                                                      const float* __restrict__ qInv,
                                                      const int* __restrict__ topi4,
                                                      float* __restrict__ topv,
                                                      int* __restrict__ topi) {
    __shared__ float sc[4][CAND];
    __shared__ int   si[4][CAND];
    const int lr = threadIdx.x >> 6;     // local row 0..3
    const int c  = threadIdx.x & 63;     // candidate slot
    const int g  = blockIdx.x * 4 + lr;
    int j = topi4[g * CAND + c];
    if ((unsigned)j >= NQ) j = 0;        // defensive clamp
    const float* ar = x + (long)qrow(g) * DD;
    const float* br = x + (long)qrow(j) * DD;
    float dot = 0.f;
    #pragma unroll 8
    for (int k = 0; k < DD; k++) dot = fmaf(ar[k], br[k], dot);
    sc[lr][c] = (dot * qInv[j]) * qInv[g];   // matches R11 epilogue order
    si[lr][c] = j;
    __syncthreads();
    if (threadIdx.x < 4) {
        const int r = threadIdx.x;
        float Lv[KNB]; int Li[KNB];
        for (int s = 0; s < KNB; s++) { Lv[s] = -INFINITY; Li[s] = 0x7fffffff; }
        for (int q = 0; q < CAND; q++) {
            float v = sc[r][q]; int idx = si[r][q];
            if (v > Lv[KNB - 1] || (v == Lv[KNB - 1] && idx < Li[KNB - 1])) {
                int p = KNB - 1;
                while (p > 0 && (Lv[p - 1] < v || (Lv[p - 1] == v && Li[p - 1] > idx))) {
                    Lv[p] = Lv[p - 1]; Li[p] = Li[p - 1]; p--;
                }
                Lv[p] = v; Li[p] = idx;
            }
        }
        const int gg = blockIdx.x * 4 + r;
        for (int s = 0; s < KNB; s++) {
            topv[gg * KNB + s] = Lv[s];
            topi[gg * KNB + s] = Li[s];
        }
    }
}

// ---------- K6: mutual-kNN softmax, adapted query, final cos sims ----------
__global__ __launch_bounds__(256) void final_kernel(const float* __restrict__ x,
                                                    const float* __restrict__ apn,
                                                    const float* __restrict__ topv,
                                                    const int* __restrict__ topi,
                                                    const float* __restrict__ tao_raw,
                                                    float* out) {
    __shared__ float tv[KNB]; __shared__ int ti[KNB]; __shared__ float w[KNB];
    __shared__ float aq[256]; __shared__ float red[256];
    int i = blockIdx.x, t = threadIdx.x;
    if (t < KNB) {
        tv[t] = topv[i * KNB + t];
        int j = topi[i * KNB + t];
        ti[t] = ((unsigned)j < NQ) ? j : 0;
    }
    __syncthreads();
    if (t < KNB) {
        int j = ti[t];
        bool mut = false;
        for (int s = 0; s < KNB; s++) mut = mut || (topi[j * KNB + s] == i);
        w[t] = mut ? tv[t] : -INFINITY;
    }
    __syncthreads();
    if (t == 0) {
        float m = -INFINITY;
        for (int s = 0; s < KNB; s++) m = fmaxf(m, w[s]);
        float e[KNB]; float Z = 0.f;
        for (int s = 0; s < KNB; s++) { e[s] = expf(w[s] - m); Z += e[s]; }
        for (int s = 0; s < KNB; s++) w[s] = e[s] / Z;
    }
    __syncthreads();
    float a = 0.f;
    for (int s = 0; s < KNB; s++) {
        float ws = w[s];
        if (ws != 0.f) a += ws * x[(long)qrow(ti[s]) * DD + t];
    }
    aq[t] = a;
    float n2 = blk_reduce_sum(a * a, red);
    float inv = 1.f / sqrtf(n2);
    int c = t >> 2, tl = t & 3;
    float sdot = 0.f;
    for (int u = 0; u < 64; u++) sdot += aq[tl * 64 + u] * apn[c * DD + tl * 64 + u];
    red[t] = sdot; __syncthreads();
    if (tl == 0) {
        float sv = red[t] + red[t + 1] + red[t + 2] + red[t + 3];
        out[i * NCLS + c] = tao_raw[0] * sv * inv;
    }
}

extern "C" void kernel_launch(void* const* d_in, const int* in_sizes, int n_in,
                              void* d_out, int out_size, void* d_ws, size_t ws_size,
                              hipStream_t stream) {
    (void)in_sizes; (void)n_in; (void)out_size;
    const float* x   = (const float*)d_in[0];
    const float* tao = (const float*)d_in[1];
    float* out = (float*)d_out;

    char* ws = (char*)d_ws;
    size_t off = 0;
    auto carve = [&](size_t bytes) {
        void* p = ws + off;
        off = (off + bytes + 255) & ~(size_t)255;
        return p;
    };
    float*          proto   = (float*)carve(NCLS * DD * 4);
    float*          pn      = (float*)carve(NCLS * DD * 4);
    float*          selfs   = (float*)carve(NCLS * 4);
    float*          qInv    = (float*)carve(NQ * 4);
    float*          pre_max = (float*)carve(NQ * 4);
    int*            pre_lab = (int*)carve(NQ * 4);
    float*          apn     = (float*)carve(NCLS * DD * 4);
    unsigned short* xh      = (unsigned short*)carve((size_t)NQ * DD * 2);
    unsigned short* xl      = (unsigned short*)carve((size_t)NQ * DD * 2);
    int*            topi4   = (int*)carve((size_t)NQ * CAND * 4);
    float*          topv    = (float*)carve((size_t)NQ * KNB * 4);
    int*            topi    = (int*)carve((size_t)NQ * KNB * 4);
    if (off > ws_size) return;

    split_kernel<<<NQ, 256, 0, stream>>>(x, xh, xl, qInv);
    proto_kernel<<<NCLS, 256, 0, stream>>>(x, proto, pn, selfs);
    presim_kernel<<<NQ, 256, 0, stream>>>(x, qInv, pn, pre_max, pre_lab);
    adapt_proto_kernel<<<NCLS, 256, 0, stream>>>(x, proto, selfs, pre_max, pre_lab, apn);
    simtopk_kernel<<<512, 256, 0, stream>>>(xh, xl, qInv, topi4);
    rescore_kernel<<<NQ / 4, 256, 0, stream>>>(x, qInv, topi4, topv, topi);
    final_kernel<<<NQ, 256, 0, stream>>>(x, apn, topv, topi, tao, out);
}

// Round 14
// 1415.642 us; speedup vs baseline: 1.0073x; 1.0073x over previous
//
#include <hip/hip_runtime.h>
#include <math.h>

#define NCLS 64
#define KS 5
#define DD 256
#define NQ 8192   // NCLS*128
#define KNB 10
#define QK 16     // per-quarter candidate list depth
#define CAND 64   // 4 quarters * QK

typedef __attribute__((ext_vector_type(8))) short short8;   // 8 bf16 bit-patterns (4 VGPRs)
typedef __attribute__((ext_vector_type(4))) float f32x4;    // MFMA C/D frag

// row index in x (fp32 row units) of query g
__device__ __forceinline__ int qrow(int g) { return (g >> 7) * 133 + KS + (g & 127); }

__device__ __forceinline__ unsigned short bf16_rne(float f) {
    unsigned int u = __float_as_uint(f);
    u += 0x7fffu + ((u >> 16) & 1u);
    return (unsigned short)(u >> 16);
}

__device__ __forceinline__ float blk_reduce_sum(float v, float* red) {
    int t = threadIdx.x;
    red[t] = v; __syncthreads();
    for (int off = 128; off > 0; off >>= 1) {
        if (t < off) red[t] += red[t + off];
        __syncthreads();
    }
    float r = red[0];
    __syncthreads();
    return r;
}

__device__ __forceinline__ float blk_reduce_max(float v, float* red) {
    int t = threadIdx.x;
    red[t] = v; __syncthreads();
    for (int off = 128; off > 0; off >>= 1) {
        if (t < off) red[t] = fmaxf(red[t], red[t + off]);
        __syncthreads();
    }
    float r = red[0];
    __syncthreads();
    return r;
}

// ---------- K0: bf16 cast of query rows (dense) + qInv ----------
__global__ __launch_bounds__(256) void split_kernel(const float* __restrict__ x,
                                                    unsigned short* __restrict__ xh,
                                                    float* __restrict__ qInv) {
    __shared__ float red[256];
    int g = blockIdx.x, t = threadIdx.x;
    float v = x[(long)qrow(g) * DD + t];
    xh[g * DD + t] = bf16_rne(v);
    float n2 = blk_reduce_sum(v * v, red);
    if (t == 0) qInv[g] = 1.f / sqrtf(n2);
}

// ---------- K1: proto, pn, self_sim ----------
__global__ __launch_bounds__(256) void proto_kernel(const float* __restrict__ x,
                                                    float* proto, float* pn, float* selfs) {
    __shared__ float red[256];
    int c = blockIdx.x, t = threadIdx.x;
    float s = 0.f;
    for (int j = 0; j < KS; j++) s += x[(long)(c * 133 + j) * DD + t];
    float p = s / 5.0f;
    proto[c * DD + t] = p;
    float n2 = blk_reduce_sum(p * p, red);
    float pv = p / sqrtf(n2);
    pn[c * DD + t] = pv;
    float ss = blk_reduce_sum(pv * pv, red);
    if (t == 0) selfs[c] = ss;
}

// ---------- K2: pre_sim argmax per query ----------
__global__ __launch_bounds__(256) void presim_kernel(const float* __restrict__ x,
                                                     const float* __restrict__ qInv,
                                                     const float* __restrict__ pn,
                                                     float* pre_max, int* pre_label) {
    __shared__ float qs[256];
    __shared__ float part[256];
    __shared__ float sims[64];
    int g = blockIdx.x, t = threadIdx.x;
    qs[t] = x[(long)qrow(g) * DD + t];
    __syncthreads();
    int c = t >> 2, tl = t & 3;
    float s = 0.f;
    for (int u = 0; u < 64; u++) s += qs[tl * 64 + u] * pn[c * DD + tl * 64 + u];
    part[t] = s; __syncthreads();
    if (tl == 0) sims[c] = part[t] + part[t + 1] + part[t + 2] + part[t + 3];
    __syncthreads();
    if (t == 0) {
        float best = sims[0]; int bi = 0;
        for (int c2 = 1; c2 < 64; c2++)
            if (sims[c2] > best) { best = sims[c2]; bi = c2; }
        pre_max[g] = best * qInv[g];
        pre_label[g] = bi;
    }
}

// ---------- K3: adapted prototypes (normalized) ----------
__global__ __launch_bounds__(256) void adapt_proto_kernel(const float* __restrict__ x,
                                                          const float* __restrict__ proto,
                                                          const float* __restrict__ selfs,
                                                          const float* __restrict__ pre_max,
                                                          const int* __restrict__ pre_label,
                                                          float* apn) {
    __shared__ float red[256];
    int c = blockIdx.x, t = threadIdx.x;
    float lm = -INFINITY;
    for (int g = t; g < NQ; g += 256)
        if (pre_label[g] == c) lm = fmaxf(lm, pre_max[g]);
    float m = fmaxf(blk_reduce_max(lm, red), selfs[c]);
    float ls = 0.f;
    for (int g = t; g < NQ; g += 256)
        if (pre_label[g] == c) ls += expf(pre_max[g] - m);
    float es = expf(selfs[c] - m);
    float Z = blk_reduce_sum(ls, red) + es;
    float acc = es * proto[c * DD + t];
    for (int g = 0; g < NQ; g++) {
        if (pre_label[g] == c)
            acc += expf(pre_max[g] - m) * x[(long)qrow(g) * DD + t];
    }
    float ap = acc / Z;
    float n2 = blk_reduce_sum(ap * ap, red);
    apn[c * DD + t] = ap / sqrtf(n2);
}

// ---------- K4: bf16 MFMA coarse scores -> per-quarter top-16 candidates ----------
// Block = 4 independent waves x 16 rows; quarter = 2048 cols in 16 macrotiles of 128.
// B frags loaded directly from global (xh L2-resident); per-wave private LDS only.
__global__ __launch_bounds__(256) void simtopk_kernel(const unsigned short* __restrict__ xh,
                                                      const float* __restrict__ qInv,
                                                      int* __restrict__ topi4) {
    __shared__ float Sw[4][16 * 132];   // per-wave score transpose, 33.8 KB
    __shared__ float lv[4][16][QK];
    __shared__ int   li[4][16][QK];     // 8 KB

    const int t = threadIdx.x;
    const int b = blockIdx.x;
    const int rb = b >> 2;
    const int qt = b & 3;
    const int row0 = rb * 64;
    const int col0 = qt * 2048;

    const int wv = t >> 6;
    const int lane = t & 63;
    const int qd = lane >> 4;
    const int nn = lane & 15;

    // per-wave list init (no cross-wave data -> no barrier needed)
    for (int s = lane; s < 16 * QK; s += 64) {
        (&lv[wv][0][0])[s] = -INFINITY;
        (&li[wv][0][0])[s] = 0;
    }

    // A fragments: lane holds A[m=nn][k=kc*32+qd*8 ..+7], rows row0+16wv..+15
    const int arow = (row0 + wv * 16 + nn) * DD;
    short8 ah[8];
    #pragma unroll
    for (int kc = 0; kc < 8; kc++)
        ah[kc] = *(const short8*)(xh + arow + kc * 32 + qd * 8);

    const float ainv = qInv[row0 + wv * 16 + nn];   // scan lanes use lane<16 -> nn==lane
    float* S = &Sw[wv][0];
    float thr = -INFINITY;

    for (int mt = 0; mt < 16; mt++) {       // 16 macrotiles of 128 cols
        const int jb = col0 + mt * 128;
        f32x4 acc[8];
        #pragma unroll
        for (int st = 0; st < 8; st++) acc[st] = (f32x4){0.f, 0.f, 0.f, 0.f};
        #pragma unroll 2
        for (int st = 0; st < 8; st++) {
            const int cb = (jb + st * 16 + nn) * DD;
            #pragma unroll
            for (int kc = 0; kc < 8; kc++) {
                short8 bfrag = *(const short8*)(xh + cb + kc * 32 + qd * 8);
                acc[st] = __builtin_amdgcn_mfma_f32_16x16x32_bf16(ah[kc], bfrag, acc[st], 0, 0, 0);
            }
        }
        // publish: C/D layout col=lane&15, row=4*qd+reg  (2-way LDS = free)
        #pragma unroll
        for (int st = 0; st < 8; st++)
            #pragma unroll
            for (int r = 0; r < 4; r++)
                S[(4 * qd + r) * 132 + st * 16 + nn] = acc[st][r];
        __syncthreads();
        if (lane < 16) {
            float* Lv = &lv[wv][lane][0];
            int*   Li = &li[wv][lane][0];
            const float* Srow = S + lane * 132;
            #pragma unroll 1
            for (int j = 0; j < 128; j++) {
                float v = Srow[j] * ainv * qInv[jb + j];
                if (v > thr) {
                    int p = QK - 1;
                    while (p > 0 && Lv[p - 1] < v) {
                        Lv[p] = Lv[p - 1]; Li[p] = Li[p - 1]; p--;
                    }
                    Lv[p] = v; Li[p] = jb + j;
                    thr = Lv[QK - 1];
                }
            }
        }
        __syncthreads();
    }

    if (lane < 16) {
        const int g = row0 + wv * 16 + lane;
        for (int s = 0; s < QK; s++)
            topi4[(g * 4 + qt) * QK + s] = li[wv][lane][s];
    }
}

// ---------- K5: exact fp32 rescoring (strict-k fmaf) + top-10 ----------
__global__ __launch_bounds__(256) void rescore_kernel(const float* __restrict__ x,
                                                      const float* __restrict__ qInv,
                                                      const int* __restrict__ topi4,
                                                      float* __restrict__ topv,
                                                      int* __restrict__ topi) {
    __shared__ float sc[4][CAND];
    __shared__ int   si[4][CAND];
    const int lr = threadIdx.x >> 6;     // local row 0..3
    const int c  = threadIdx.x & 63;     // candidate slot
    const int g  = blockIdx.x * 4 + lr;
    int j = topi4[g * CAND + c];
    if ((unsigned)j >= NQ) j = 0;        // defensive clamp
    const float* ar = x + (long)qrow(g) * DD;
    const float* br = x + (long)qrow(j) * DD;
    float dot = 0.f;
    #pragma unroll 8
    for (int k = 0; k < DD; k++) dot = fmaf(ar[k], br[k], dot);
    sc[lr][c] = (dot * qInv[j]) * qInv[g];
    si[lr][c] = j;
    __syncthreads();
    if (threadIdx.x < 4) {
        const int r = threadIdx.x;
        float Lv[KNB]; int Li[KNB];
        for (int s = 0; s < KNB; s++) { Lv[s] = -INFINITY; Li[s] = 0x7fffffff; }
        for (int q = 0; q < CAND; q++) {
            float v = sc[r][q]; int idx = si[r][q];
            if (v > Lv[KNB - 1] || (v == Lv[KNB - 1] && idx < Li[KNB - 1])) {
                int p = KNB - 1;
                while (p > 0 && (Lv[p - 1] < v || (Lv[p - 1] == v && Li[p - 1] > idx))) {
                    Lv[p] = Lv[p - 1]; Li[p] = Li[p - 1]; p--;
                }
                Lv[p] = v; Li[p] = idx;
            }
        }
        const int gg = blockIdx.x * 4 + r;
        for (int s = 0; s < KNB; s++) {
            topv[gg * KNB + s] = Lv[s];
            topi[gg * KNB + s] = Li[s];
        }
    }
}

// ---------- K6: mutual-kNN softmax, adapted query, final cos sims ----------
__global__ __launch_bounds__(256) void final_kernel(const float* __restrict__ x,
                                                    const float* __restrict__ apn,
                                                    const float* __restrict__ topv,
                                                    const int* __restrict__ topi,
                                                    const float* __restrict__ tao_raw,
                                                    float* out) {
    __shared__ float tv[KNB]; __shared__ int ti[KNB]; __shared__ float w[KNB];
    __shared__ float aq[256]; __shared__ float red[256];
    int i = blockIdx.x, t = threadIdx.x;
    if (t < KNB) {
        tv[t] = topv[i * KNB + t];
        int j = topi[i * KNB + t];
        ti[t] = ((unsigned)j < NQ) ? j : 0;
    }
    __syncthreads();
    if (t < KNB) {
        int j = ti[t];
        bool mut = false;
        for (int s = 0; s < KNB; s++) mut = mut || (topi[j * KNB + s] == i);
        w[t] = mut ? tv[t] : -INFINITY;
    }
    __syncthreads();
    if (t == 0) {
        float m = -INFINITY;
        for (int s = 0; s < KNB; s++) m = fmaxf(m, w[s]);
        float e[KNB]; float Z = 0.f;
        for (int s = 0; s < KNB; s++) { e[s] = expf(w[s] - m); Z += e[s]; }
        for (int s = 0; s < KNB; s++) w[s] = e[s] / Z;
    }
    __syncthreads();
    float a = 0.f;
    for (int s = 0; s < KNB; s++) {
        float ws = w[s];
        if (ws != 0.f) a += ws * x[(long)qrow(ti[s]) * DD + t];
    }
    aq[t] = a;
    float n2 = blk_reduce_sum(a * a, red);
    float inv = 1.f / sqrtf(n2);
    int c = t >> 2, tl = t & 3;
    float sdot = 0.f;
    for (int u = 0; u < 64; u++) sdot += aq[tl * 64 + u] * apn[c * DD + tl * 64 + u];
    red[t] = sdot; __syncthreads();
    if (tl == 0) {
        float sv = red[t] + red[t + 1] + red[t + 2] + red[t + 3];
        out[i * NCLS + c] = tao_raw[0] * sv * inv;
    }
}

extern "C" void kernel_launch(void* const* d_in, const int* in_sizes, int n_in,
                              void* d_out, int out_size, void* d_ws, size_t ws_size,
                              hipStream_t stream) {
    (void)in_sizes; (void)n_in; (void)out_size;
    const float* x   = (const float*)d_in[0];
    const float* tao = (const float*)d_in[1];
    float* out = (float*)d_out;

    char* ws = (char*)d_ws;
    size_t off = 0;
    auto carve = [&](size_t bytes) {
        void* p = ws + off;
        off = (off + bytes + 255) & ~(size_t)255;
        return p;
    };
    float*          proto   = (float*)carve(NCLS * DD * 4);
    float*          pn      = (float*)carve(NCLS * DD * 4);
    float*          selfs   = (float*)carve(NCLS * 4);
    float*          qInv    = (float*)carve(NQ * 4);
    float*          pre_max = (float*)carve(NQ * 4);
    int*            pre_lab = (int*)carve(NQ * 4);
    float*          apn     = (float*)carve(NCLS * DD * 4);
    unsigned short* xh      = (unsigned short*)carve((size_t)NQ * DD * 2);
    int*            topi4   = (int*)carve((size_t)NQ * CAND * 4);
    float*          topv    = (float*)carve((size_t)NQ * KNB * 4);
    int*            topi    = (int*)carve((size_t)NQ * KNB * 4);
    if (off > ws_size) return;

    split_kernel<<<NQ, 256, 0, stream>>>(x, xh, qInv);
    proto_kernel<<<NCLS, 256, 0, stream>>>(x, proto, pn, selfs);
    presim_kernel<<<NQ, 256, 0, stream>>>(x, qInv, pn, pre_max, pre_lab);
    adapt_proto_kernel<<<NCLS, 256, 0, stream>>>(x, proto, selfs, pre_max, pre_lab, apn);
    simtopk_kernel<<<512, 256, 0, stream>>>(xh, qInv, topi4);
    rescore_kernel<<<NQ / 4, 256, 0, stream>>>(x, qInv, topi4, topv, topi);
    final_kernel<<<NQ, 256, 0, stream>>>(x, apn, topv, topi, tao, out);
}

// Round 15
// 938.735 us; speedup vs baseline: 1.5190x; 1.5080x over previous
//
#include <hip/hip_runtime.h>
#include <math.h>

#define NCLS 64
#define KS 5
#define DD 256
#define NQ 8192   // NCLS*128
#define KNB 10
#define QK 16     // per-quarter candidate list depth
#define CAND 64   // 4 quarters * QK

typedef __attribute__((ext_vector_type(8))) short short8;   // 8 bf16 bit-patterns (4 VGPRs)
typedef __attribute__((ext_vector_type(4))) float f32x4;    // MFMA C/D frag

// row index in x (fp32 row units) of query g
__device__ __forceinline__ int qrow(int g) { return (g >> 7) * 133 + KS + (g & 127); }

__device__ __forceinline__ unsigned short bf16_rne(float f) {
    unsigned int u = __float_as_uint(f);
    u += 0x7fffu + ((u >> 16) & 1u);
    return (unsigned short)(u >> 16);
}

__device__ __forceinline__ float blk_reduce_sum(float v, float* red) {
    int t = threadIdx.x;
    red[t] = v; __syncthreads();
    for (int off = 128; off > 0; off >>= 1) {
        if (t < off) red[t] += red[t + off];
        __syncthreads();
    }
    float r = red[0];
    __syncthreads();
    return r;
}

__device__ __forceinline__ float blk_reduce_max(float v, float* red) {
    int t = threadIdx.x;
    red[t] = v; __syncthreads();
    for (int off = 128; off > 0; off >>= 1) {
        if (t < off) red[t] = fmaxf(red[t], red[t + off]);
        __syncthreads();
    }
    float r = red[0];
    __syncthreads();
    return r;
}

// ---------- K0: bf16 cast of query rows (dense) + qInv ----------
__global__ __launch_bounds__(256) void split_kernel(const float* __restrict__ x,
                                                    unsigned short* __restrict__ xh,
                                                    float* __restrict__ qInv) {
    __shared__ float red[256];
    int g = blockIdx.x, t = threadIdx.x;
    float v = x[(long)qrow(g) * DD + t];
    xh[g * DD + t] = bf16_rne(v);
    float n2 = blk_reduce_sum(v * v, red);
    if (t == 0) qInv[g] = 1.f / sqrtf(n2);
}

// ---------- K1: proto, pn, self_sim ----------
__global__ __launch_bounds__(256) void proto_kernel(const float* __restrict__ x,
                                                    float* proto, float* pn, float* selfs) {
    __shared__ float red[256];
    int c = blockIdx.x, t = threadIdx.x;
    float s = 0.f;
    for (int j = 0; j < KS; j++) s += x[(long)(c * 133 + j) * DD + t];
    float p = s / 5.0f;
    proto[c * DD + t] = p;
    float n2 = blk_reduce_sum(p * p, red);
    float pv = p / sqrtf(n2);
    pn[c * DD + t] = pv;
    float ss = blk_reduce_sum(pv * pv, red);
    if (t == 0) selfs[c] = ss;
}

// ---------- K2: pre_sim argmax per query ----------
__global__ __launch_bounds__(256) void presim_kernel(const float* __restrict__ x,
                                                     const float* __restrict__ qInv,
                                                     const float* __restrict__ pn,
                                                     float* pre_max, int* pre_label) {
    __shared__ float qs[256];
    __shared__ float part[256];
    __shared__ float sims[64];
    int g = blockIdx.x, t = threadIdx.x;
    qs[t] = x[(long)qrow(g) * DD + t];
    __syncthreads();
    int c = t >> 2, tl = t & 3;
    float s = 0.f;
    for (int u = 0; u < 64; u++) s += qs[tl * 64 + u] * pn[c * DD + tl * 64 + u];
    part[t] = s; __syncthreads();
    if (tl == 0) sims[c] = part[t] + part[t + 1] + part[t + 2] + part[t + 3];
    __syncthreads();
    if (t == 0) {
        float best = sims[0]; int bi = 0;
        for (int c2 = 1; c2 < 64; c2++)
            if (sims[c2] > best) { best = sims[c2]; bi = c2; }
        pre_max[g] = best * qInv[g];
        pre_label[g] = bi;
    }
}

// ---------- K3: adapted prototypes — LDS-compacted member list ----------
__global__ __launch_bounds__(256) void adapt_proto_kernel(const float* __restrict__ x,
                                                          const float* __restrict__ proto,
                                                          const float* __restrict__ selfs,
                                                          const float* __restrict__ pre_max,
                                                          const int* __restrict__ pre_label,
                                                          float* apn) {
    __shared__ int lst[NQ];     // 32 KB (worst case: all queries in one class)
    __shared__ float red[256];
    __shared__ int cnt_s;
    int c = blockIdx.x, t = threadIdx.x;
    if (t == 0) cnt_s = 0;
    __syncthreads();
    float lm = -INFINITY;
    for (int g = t; g < NQ; g += 256) {
        if (pre_label[g] == c) {
            int p = atomicAdd(&cnt_s, 1);
            lst[p] = g;
            lm = fmaxf(lm, pre_max[g]);
        }
    }
    float m = fmaxf(blk_reduce_max(lm, red), selfs[c]);   // barrier publishes lst/cnt_s
    int cnt = cnt_s;
    float ls = 0.f;
    for (int e = t; e < cnt; e += 256) ls += expf(pre_max[lst[e]] - m);
    float es = expf(selfs[c] - m);
    float Z = blk_reduce_sum(ls, red) + es;
    float acc = es * proto[c * DD + t];
    #pragma unroll 2
    for (int e = 0; e < cnt; e++) {
        int g = lst[e];
        acc += expf(pre_max[g] - m) * x[(long)qrow(g) * DD + t];
    }
    float ap = acc / Z;
    float n2 = blk_reduce_sum(ap * ap, red);
    apn[c * DD + t] = ap / sqrtf(n2);
}

// ---------- K4: bf16 MFMA coarse scores -> per-quarter top-16 candidates ----------
// Block = 4 independent waves x 16 rows; quarter = 2048 cols, 16 macrotiles of 128.
// NO barriers in the main loop: all LDS is wave-private (in-order per-wave DS ops).
// Scan: all 64 lanes (4 lanes/row x 32 cols), top-16 lists in REGISTERS (bubble insert).
__global__ __launch_bounds__(256) void simtopk_kernel(const unsigned short* __restrict__ xh,
                                                      const float* __restrict__ qInv,
                                                      int* __restrict__ topi4) {
    __shared__ float Sw[4][2112];   // per-wave scores 16x132 (reused as merge dump) 33.8 KB
    __shared__ float qc[2048];      // quarter's qInv, 8 KB

    const int t = threadIdx.x;
    const int b = blockIdx.x;
    const int rb = b >> 2;
    const int qt = b & 3;
    const int row0 = rb * 64;
    const int col0 = qt * 2048;

    const int wv = t >> 6;
    const int lane = t & 63;
    const int qd = lane >> 4;
    const int nn = lane & 15;

    for (int i = t; i < 2048; i += 256) qc[i] = qInv[col0 + i];
    __syncthreads();   // the only block-wide barrier

    // A fragments: lane holds A[m=nn][k=kc*32+qd*8 ..+7], rows row0+16wv..+15
    const int arow = (row0 + wv * 16 + nn) * DD;
    short8 ah[8];
    #pragma unroll
    for (int kc = 0; kc < 8; kc++)
        ah[kc] = *(const short8*)(xh + arow + kc * 32 + qd * 8);

    const int srow = lane >> 2;    // scan row 0..15
    const int slot = lane & 3;     // scan column slot
    const float ainv = qInv[row0 + wv * 16 + srow];

    float Lv[QK]; int Li[QK];
    #pragma unroll
    for (int s = 0; s < QK; s++) { Lv[s] = -INFINITY; Li[s] = 0; }
    float thr = -INFINITY;

    float* S = &Sw[wv][0];

    for (int mt = 0; mt < 16; mt++) {
        const int jb = col0 + mt * 128;
        #pragma unroll 2
        for (int st = 0; st < 8; st++) {
            f32x4 acc = {0.f, 0.f, 0.f, 0.f};
            const int cb = (jb + st * 16 + nn) * DD;
            #pragma unroll
            for (int kc = 0; kc < 8; kc++) {
                short8 bfrag = *(const short8*)(xh + cb + kc * 32 + qd * 8);
                acc = __builtin_amdgcn_mfma_f32_16x16x32_bf16(ah[kc], bfrag, acc, 0, 0, 0);
            }
            // C/D: col=nn, row=4qd+r. Fold qInv_col here. (2-way LDS writes = free)
            float qj = qc[mt * 128 + st * 16 + nn];
            #pragma unroll
            for (int r = 0; r < 4; r++)
                S[(4 * qd + r) * 132 + st * 16 + nn] = acc[r] * qj;
        }
        // wave-private scan: lane (srow,slot) handles cols jj*4+slot (bank = lane+4jj: 2-way)
        #pragma unroll 4
        for (int jj = 0; jj < 32; jj++) {
            const int j = jj * 4 + slot;
            float v = S[srow * 132 + j] * ainv;
            if (v > thr) {
                float cv = v; int ci = jb + j;
                #pragma unroll
                for (int p = 0; p < QK; p++) {   // bubble insert, register-resident
                    bool sw = (cv > Lv[p]);
                    float tv = Lv[p]; int tix = Li[p];
                    Lv[p] = sw ? cv : Lv[p];
                    Li[p] = sw ? ci : Li[p];
                    cv = sw ? tv : cv;
                    ci = sw ? tix : ci;
                }
                thr = Lv[QK - 1];
            }
        }
    }

    // dump lists to wave-private LDS, then lanes 0..15 merge their row's 4 slot-lists
    float* dv = &Sw[wv][0];
    int*   di = (int*)&Sw[wv][1024];
    #pragma unroll
    for (int s = 0; s < QK; s++) { dv[lane * QK + s] = Lv[s]; di[lane * QK + s] = Li[s]; }
    if (lane < 16) {
        const int g = row0 + wv * 16 + lane;
        int p0 = 0, p1 = 0, p2 = 0, p3 = 0;
        const int base = lane * 4 * QK;
        for (int s = 0; s < QK; s++) {
            float v0 = (p0 < QK) ? dv[base + 0 * QK + p0] : -INFINITY;
            float v1 = (p1 < QK) ? dv[base + 1 * QK + p1] : -INFINITY;
            float v2 = (p2 < QK) ? dv[base + 2 * QK + p2] : -INFINITY;
            float v3 = (p3 < QK) ? dv[base + 3 * QK + p3] : -INFINITY;
            int i0 = (p0 < QK) ? di[base + 0 * QK + p0] : 0x7fffffff;
            int i1 = (p1 < QK) ? di[base + 1 * QK + p1] : 0x7fffffff;
            int i2 = (p2 < QK) ? di[base + 2 * QK + p2] : 0x7fffffff;
            int i3 = (p3 < QK) ? di[base + 3 * QK + p3] : 0x7fffffff;
            float bv = v0; int bi = i0; int bw = 0;
            if (v1 > bv || (v1 == bv && i1 < bi)) { bv = v1; bi = i1; bw = 1; }
            if (v2 > bv || (v2 == bv && i2 < bi)) { bv = v2; bi = i2; bw = 2; }
            if (v3 > bv || (v3 == bv && i3 < bi)) { bv = v3; bi = i3; bw = 3; }
            topi4[(g * 4 + qt) * QK + s] = bi;
            if (bw == 0) p0++; else if (bw == 1) p1++; else if (bw == 2) p2++; else p3++;
        }
    }
}

// ---------- K5: exact fp32 rescoring (strict-k fmaf) + top-10 ----------
__global__ __launch_bounds__(256) void rescore_kernel(const float* __restrict__ x,
                                                      const float* __restrict__ qInv,
                                                      const int* __restrict__ topi4,
                                                      float* __restrict__ topv,
                                                      int* __restrict__ topi) {
    __shared__ float sc[4][CAND];
    __shared__ int   si[4][CAND];
    const int lr = threadIdx.x >> 6;     // local row 0..3
    const int c  = threadIdx.x & 63;     // candidate slot
    const int g  = blockIdx.x * 4 + lr;
    int j = topi4[g * CAND + c];
    if ((unsigned)j >= NQ) j = 0;        // defensive clamp
    const float* ar = x + (long)qrow(g) * DD;
    const float* br = x + (long)qrow(j) * DD;
    float dot = 0.f;
    #pragma unroll 8
    for (int k = 0; k < DD; k++) dot = fmaf(ar[k], br[k], dot);
    sc[lr][c] = (dot * qInv[j]) * qInv[g];
    si[lr][c] = j;
    __syncthreads();
    if (threadIdx.x < 4) {
        const int r = threadIdx.x;
        float Lv[KNB]; int Li[KNB];
        for (int s = 0; s < KNB; s++) { Lv[s] = -INFINITY; Li[s] = 0x7fffffff; }
        for (int q = 0; q < CAND; q++) {
            float v = sc[r][q]; int idx = si[r][q];
            if (v > Lv[KNB - 1] || (v == Lv[KNB - 1] && idx < Li[KNB - 1])) {
                int p = KNB - 1;
                while (p > 0 && (Lv[p - 1] < v || (Lv[p - 1] == v && Li[p - 1] > idx))) {
                    Lv[p] = Lv[p - 1]; Li[p] = Li[p - 1]; p--;
                }
                Lv[p] = v; Li[p] = idx;
            }
        }
        const int gg = blockIdx.x * 4 + r;
        for (int s = 0; s < KNB; s++) {
            topv[gg * KNB + s] = Lv[s];
            topi[gg * KNB + s] = Li[s];
        }
    }
}

// ---------- K6: mutual-kNN softmax, adapted query, final cos sims ----------
__global__ __launch_bounds__(256) void final_kernel(const float* __restrict__ x,
                                                    const float* __restrict__ apn,
                                                    const float* __restrict__ topv,
                                                    const int* __restrict__ topi,
                                                    const float* __restrict__ tao_raw,
                                                    float* out) {
    __shared__ float tv[KNB]; __shared__ int ti[KNB]; __shared__ float w[KNB];
    __shared__ float aq[256]; __shared__ float red[256];
    int i = blockIdx.x, t = threadIdx.x;
    if (t < KNB) {
        tv[t] = topv[i * KNB + t];
        int j = topi[i * KNB + t];
        ti[t] = ((unsigned)j < NQ) ? j : 0;
    }
    __syncthreads();
    if (t < KNB) {
        int j = ti[t];
        bool mut = false;
        for (int s = 0; s < KNB; s++) mut = mut || (topi[j * KNB + s] == i);
        w[t] = mut ? tv[t] : -INFINITY;
    }
    __syncthreads();
    if (t == 0) {
        float m = -INFINITY;
        for (int s = 0; s < KNB; s++) m = fmaxf(m, w[s]);
        float e[KNB]; float Z = 0.f;
        for (int s = 0; s < KNB; s++) { e[s] = expf(w[s] - m); Z += e[s]; }
        for (int s = 0; s < KNB; s++) w[s] = e[s] / Z;
    }
    __syncthreads();
    float a = 0.f;
    for (int s = 0; s < KNB; s++) {
        float ws = w[s];
        if (ws != 0.f) a += ws * x[(long)qrow(ti[s]) * DD + t];
    }
    aq[t] = a;
    float n2 = blk_reduce_sum(a * a, red);
    float inv = 1.f / sqrtf(n2);
    int c = t >> 2, tl = t & 3;
    float sdot = 0.f;
    for (int u = 0; u < 64; u++) sdot += aq[tl * 64 + u] * apn[c * DD + tl * 64 + u];
    red[t] = sdot; __syncthreads();
    if (tl == 0) {
        float sv = red[t] + red[t + 1] + red[t + 2] + red[t + 3];
        out[i * NCLS + c] = tao_raw[0] * sv * inv;
    }
}

extern "C" void kernel_launch(void* const* d_in, const int* in_sizes, int n_in,
                              void* d_out, int out_size, void* d_ws, size_t ws_size,
                              hipStream_t stream) {
    (void)in_sizes; (void)n_in; (void)out_size;
    const float* x   = (const float*)d_in[0];
    const float* tao = (const float*)d_in[1];
    float* out = (float*)d_out;

    char* ws = (char*)d_ws;
    size_t off = 0;
    auto carve = [&](size_t bytes) {
        void* p = ws + off;
        off = (off + bytes + 255) & ~(size_t)255;
        return p;
    };
    float*          proto   = (float*)carve(NCLS * DD * 4);
    float*          pn      = (float*)carve(NCLS * DD * 4);
    float*          selfs   = (float*)carve(NCLS * 4);
    float*          qInv    = (float*)carve(NQ * 4);
    float*          pre_max = (float*)carve(NQ * 4);
    int*            pre_lab = (int*)carve(NQ * 4);
    float*          apn     = (float*)carve(NCLS * DD * 4);
    unsigned short* xh      = (unsigned short*)carve((size_t)NQ * DD * 2);
    int*            topi4   = (int*)carve((size_t)NQ * CAND * 4);
    float*          topv    = (float*)carve((size_t)NQ * KNB * 4);
    int*            topi    = (int*)carve((size_t)NQ * KNB * 4);
    if (off > ws_size) return;

    split_kernel<<<NQ, 256, 0, stream>>>(x, xh, qInv);
    proto_kernel<<<NCLS, 256, 0, stream>>>(x, proto, pn, selfs);
    presim_kernel<<<NQ, 256, 0, stream>>>(x, qInv, pn, pre_max, pre_lab);
    adapt_proto_kernel<<<NCLS, 256, 0, stream>>>(x, proto, selfs, pre_max, pre_lab, apn);
    simtopk_kernel<<<512, 256, 0, stream>>>(xh, qInv, topi4);
    rescore_kernel<<<NQ / 4, 256, 0, stream>>>(x, qInv, topi4, topv, topi);
    final_kernel<<<NQ, 256, 0, stream>>>(x, apn, topv, topi, tao, out);
}